// Round 3
// baseline (2623.334 us; speedup 1.0000x reference)
//
#include <hip/hip_runtime.h>
#include <math.h>

#define B_    16
#define N_    1024
#define G_    16      // blocks per batch
#define ITERS 100

// ws layout: [cnt: B_*ITERS u32, pad to 8192][mu_den: 4*B_*N_ f32][nug: B_*N_ f32]
#define MUDEN_OFF   8192
#define MUDEN_BYTES (4 * B_ * N_ * 4)
#define NUG_OFF     (MUDEN_OFF + MUDEN_BYTES)
#define ZERO_BYTES  NUG_OFF            // memset cnt + mu_den (all 4 buffers)

__device__ __forceinline__ float fast_div(float num, float den) {
    float r = __builtin_amdgcn_rcpf(den);
    r = r * (2.0f - den * r);          // one Newton step -> ~full fp32 accuracy
    return num * r;
}

// R1's proven layout (0 bank conflicts): 1024 threads, u[4][16] per thread,
// rows 64g+4w+rr, cols l+64q. u lands in AGPRs (unified file) - fine, VALU
// has huge headroom. R3 changes ONLY the inter-block exchange machinery.
__global__ __launch_bounds__(1024, 4)
void sinkhorn_kernel(const float* __restrict__ C, float* __restrict__ out,
                     float* __restrict__ mu_den, float* __restrict__ nug,
                     unsigned int* __restrict__ cnt)
{
    __shared__ float slab[N_];   // per-block column partials (ds_add_f32)
    __shared__ float mu_s[N_];   // current mu

    const int tid = threadIdx.x;
    const int w   = tid >> 6;          // wave 0..15 -> 4-row group
    const int l   = tid & 63;
    // XCD-affinity swizzle: batch b's 16 blocks share bid%8 -> same XCD L2
    const int bid = blockIdx.x;
    const int xx = bid & 7, ss = bid >> 3;
    const int b = xx + ((ss >> 4) << 3);
    const int g = ss & 15;
    const int row0 = 64 * g + 4 * w;
    const float cons = 1.0f / 1024.0f;

    // ---- one-time: U tile = exp(-C/eps) into registers/AGPRs ----
    float u[4][16];
    {
        const float* Cb = C + (size_t)b * N_ * N_ + (size_t)row0 * N_ + l;
        #pragma unroll
        for (int rr = 0; rr < 4; ++rr)
            #pragma unroll
            for (int q = 0; q < 16; ++q)
                u[rr][q] = expf(-20.0f * Cb[(size_t)rr * N_ + 64 * q]);
    }

    slab[tid] = 0.0f;
    mu_s[tid] = cons;
    __syncthreads();

    for (int it = 0; it < ITERS; ++it) {
        // ---- Phase A: s_i = sum_j U_ij * mu_j (conflict-free LDS reads) ----
        float a0 = 0.f, a1 = 0.f, a2 = 0.f, a3 = 0.f;
        #pragma unroll
        for (int q = 0; q < 16; ++q) {
            float m = mu_s[l + 64 * q];
            a0 += u[0][q] * m;
            a1 += u[1][q] * m;
            a2 += u[2][q] * m;
            a3 += u[3][q] * m;
        }
        #pragma unroll
        for (int off = 1; off < 64; off <<= 1) {
            a0 += __shfl_xor(a0, off, 64);
            a1 += __shfl_xor(a1, off, 64);
            a2 += __shfl_xor(a2, off, 64);
            a3 += __shfl_xor(a3, off, 64);
        }
        float nu0 = fast_div(cons, a0);
        float nu1 = fast_div(cons, a1);
        float nu2 = fast_div(cons, a2);
        float nu3 = fast_div(cons, a3);

        if (it == ITERS - 1 && l < 4) {     // publish final nu (coherent store)
            float nv = (l == 0) ? nu0 : (l == 1) ? nu1 : (l == 2) ? nu2 : nu3;
            __hip_atomic_store(&nug[b * N_ + row0 + l], nv,
                               __ATOMIC_RELAXED, __HIP_MEMORY_SCOPE_AGENT);
        }

        // ---- Phase B: column partials via LDS float atomics ----
        #pragma unroll
        for (int q = 0; q < 16; ++q) {
            float p = u[0][q]*nu0 + u[1][q]*nu1 + u[2][q]*nu2 + u[3][q]*nu3;
            atomicAdd(&slab[l + 64 * q], p);     // ds_add_f32, conflict-free
        }
        __syncthreads();                    // S1: slab complete

        // thread tid is sole reader of slab[tid]; re-zero for next iter
        float v = slab[tid];
        slab[tid] = 0.0f;
        const int buf = it & 3;
        unsafeAtomicAdd(&mu_den[((size_t)buf * B_ + b) * N_ + tid], v);
        __syncthreads();                    // S2: drains vmcnt (atomics issued)

        // ---- relaxed-poll device barrier for batch b ----
        if (tid == 0) {
            unsigned int* c = &cnt[b * ITERS + it];
            __builtin_amdgcn_fence(__ATOMIC_RELEASE, "agent");   // once
            __hip_atomic_fetch_add(c, 1u, __ATOMIC_RELAXED, __HIP_MEMORY_SCOPE_AGENT);
            while (__hip_atomic_load(c, __ATOMIC_RELAXED, __HIP_MEMORY_SCOPE_AGENT) < G_)
                __builtin_amdgcn_s_sleep(1);
            __builtin_amdgcn_fence(__ATOMIC_ACQUIRE, "agent");   // once
        }
        __syncthreads();                    // S3

        // ---- read back full denominator, form new mu; zero buffer it+2 ----
        float den = __hip_atomic_load(&mu_den[((size_t)buf * B_ + b) * N_ + tid],
                                      __ATOMIC_RELAXED, __HIP_MEMORY_SCOPE_AGENT);
        mu_s[tid] = fast_div(cons, den);
        if (tid < 64)   // my block's 1/16 share of the buffer used at it+2
            __hip_atomic_store(&mu_den[((size_t)((it + 2) & 3) * B_ + b) * N_ + 64 * g + tid],
                               0.0f, __ATOMIC_RELAXED, __HIP_MEMORY_SCOPE_AGENT);
        __syncthreads();                    // S4: mu_s ready
    }

    // ---- epilogue: T_ij = mu_i * U_ij * nu_j ----
    float mu_i[4];
    #pragma unroll
    for (int rr = 0; rr < 4; ++rr)
        mu_i[rr] = mu_s[row0 + rr];        // broadcast read

    float* ob = out + (size_t)b * N_ * N_ + (size_t)row0 * N_ + l;
    #pragma unroll
    for (int q = 0; q < 16; ++q) {
        float nuv = __hip_atomic_load(&nug[b * N_ + l + 64 * q],
                                      __ATOMIC_RELAXED, __HIP_MEMORY_SCOPE_AGENT);
        #pragma unroll
        for (int rr = 0; rr < 4; ++rr)
            ob[(size_t)rr * N_ + 64 * q] = mu_i[rr] * u[rr][q] * nuv;
    }
}

extern "C" void kernel_launch(void* const* d_in, const int* in_sizes, int n_in,
                              void* d_out, int out_size, void* d_ws, size_t ws_size,
                              hipStream_t stream) {
    const float* C = (const float*)d_in[2];     // (B, N, N); x,y unused
    float* out = (float*)d_out;

    unsigned char* ws = (unsigned char*)d_ws;
    unsigned int* cnt = (unsigned int*)ws;
    float* mu_den = (float*)(ws + MUDEN_OFF);
    float* nug    = (float*)(ws + NUG_OFF);

    // cnt and all 4 mu_den buffers must start at zero
    hipMemsetAsync(ws, 0, ZERO_BYTES, stream);
    hipLaunchKernelGGL(sinkhorn_kernel, dim3(256), dim3(1024), 0, stream,
                       C, out, mu_den, nug, cnt);
}

// Round 4
// 512.919 us; speedup vs baseline: 5.1145x; 5.1145x over previous
//
#include <hip/hip_runtime.h>
#include <math.h>

#define B_    16
#define N_    1024
#define G_    16      // blocks per batch
#define ITERS 100

// ws layout: [cnt: B_*ITERS u32, pad to 8192][gpart: 2*B_*G_*N_ f32][nug: B_*N_ f32]
#define CNT_BYTES   (B_ * ITERS * 4)
#define GPART_OFF   8192
#define NUG_OFF     (GPART_OFF + 2 * B_ * G_ * N_ * 4)

__device__ __forceinline__ float fast_div(float num, float den) {
    float r = __builtin_amdgcn_rcpf(den);
    r = r * (2.0f - den * r);      // one Newton step -> ~full fp32 accuracy
    return num * r;
}

// R1's proven conflict-free layout. R4's ONLY change: the inter-block exchange
// is 100% agent-scope relaxed atomics -> ZERO fences -> no per-iteration L2
// writeback/invalidate scans (the R1/R3 ~20us/iter floor).
// Ordering argument: __syncthreads() emits s_waitcnt vmcnt(0) per wave before
// s_barrier, so all partial stores have reached the coherence point before
// tid 0 issues the arrival add; readers issue loads only after the poll load
// observes all 16 arrivals (data-dependent branch).
__global__ __launch_bounds__(1024, 4)
void sinkhorn_kernel(const float* __restrict__ C, float* __restrict__ out,
                     float* __restrict__ gpart, float* __restrict__ nug,
                     unsigned int* __restrict__ cnt)
{
    // 64 KB LDS: part[w][j] partial slabs; mu aliases row 15 (column j of
    // part is only ever read by thread j before mu_s[j] is written - safe).
    __shared__ float part[16 * 1024];
    float* mu_s = &part[15 * 1024];

    const int tid = threadIdx.x;
    const int w   = tid >> 6;        // wave 0..15 -> 4-row group
    const int l   = tid & 63;
    // XCD-affinity swizzle: batch b's 16 blocks share bid%8 -> same XCD L2
    const int bid = blockIdx.x;
    const int xx = bid & 7, ss = bid >> 3;
    const int b = xx + ((ss >> 4) << 3);
    const int g = ss & 15;
    const int row0 = 64 * g + 4 * w;
    const float cons = 1.0f / 1024.0f;

    // ---- one-time: U tile = exp(-C/eps) into registers ----
    float u[4][16];
    {
        const float* Cb = C + (size_t)b * N_ * N_ + (size_t)row0 * N_ + l;
        #pragma unroll
        for (int rr = 0; rr < 4; ++rr)
            #pragma unroll
            for (int q = 0; q < 16; ++q)
                u[rr][q] = expf(-20.0f * Cb[(size_t)rr * N_ + 64 * q]);
    }

    mu_s[tid] = cons;
    __syncthreads();

    for (int it = 0; it < ITERS; ++it) {
        // ---- Phase A: s_i = sum_j U_ij * mu_j (conflict-free LDS reads) ----
        float a0 = 0.f, a1 = 0.f, a2 = 0.f, a3 = 0.f;
        #pragma unroll
        for (int q = 0; q < 16; ++q) {
            float m = mu_s[l + 64 * q];
            a0 += u[0][q] * m;
            a1 += u[1][q] * m;
            a2 += u[2][q] * m;
            a3 += u[3][q] * m;
        }
        #pragma unroll
        for (int off = 1; off < 64; off <<= 1) {
            a0 += __shfl_xor(a0, off, 64);
            a1 += __shfl_xor(a1, off, 64);
            a2 += __shfl_xor(a2, off, 64);
            a3 += __shfl_xor(a3, off, 64);
        }
        float nu0 = fast_div(cons, a0);
        float nu1 = fast_div(cons, a1);
        float nu2 = fast_div(cons, a2);
        float nu3 = fast_div(cons, a3);

        if (it == ITERS - 1 && l < 4) {   // publish final nu chunk (coherent)
            float nv = (l == 0) ? nu0 : (l == 1) ? nu1 : (l == 2) ? nu2 : nu3;
            __hip_atomic_store(&nug[b * N_ + row0 + l], nv,
                               __ATOMIC_RELAXED, __HIP_MEMORY_SCOPE_AGENT);
        }

        __syncthreads();   // all phase-A mu reads done before part[15] clobbered

        // ---- Phase B: per-wave column partials -> LDS slab (conflict-free) ----
        #pragma unroll
        for (int q = 0; q < 16; ++q) {
            float p = u[0][q]*nu0 + u[1][q]*nu1 + u[2][q]*nu2 + u[3][q]*nu3;
            part[w * 1024 + l + 64 * q] = p;
        }
        __syncthreads();   // S1: slabs complete

        // column sums across 16 slabs -> this block's partial for column tid
        const int buf = it & 1;
        {
            float ssum = 0.f;
            #pragma unroll
            for (int w2 = 0; w2 < 16; ++w2)
                ssum += part[w2 * 1024 + tid];      // conflict-free
            __hip_atomic_store(&gpart[(((size_t)buf * B_ + b) * G_ + g) * N_ + tid],
                               ssum, __ATOMIC_RELAXED, __HIP_MEMORY_SCOPE_AGENT);
        }

        // ---- fence-free device barrier among the 16 blocks of batch b ----
        __syncthreads();   // S2: each wave's vmcnt(0) -> stores at coherence pt
        if (tid == 0) {
            unsigned int* c = &cnt[b * ITERS + it];
            __hip_atomic_fetch_add(c, 1u, __ATOMIC_RELAXED, __HIP_MEMORY_SCOPE_AGENT);
            while (__hip_atomic_load(c, __ATOMIC_RELAXED, __HIP_MEMORY_SCOPE_AGENT) < G_)
                __builtin_amdgcn_s_sleep(1);
        }
        __syncthreads();   // S3

        // ---- reduce 16 block-partials -> new mu (redundant per block) ----
        {
            float s2 = 0.f;
            #pragma unroll
            for (int g2 = 0; g2 < 16; ++g2)
                s2 += __hip_atomic_load(&gpart[(((size_t)buf * B_ + b) * G_ + g2) * N_ + tid],
                                        __ATOMIC_RELAXED, __HIP_MEMORY_SCOPE_AGENT);
            mu_s[tid] = fast_div(cons, s2);   // safe: column tid is mine alone
        }
        __syncthreads();   // S4: mu_s ready for next phase A
    }

    // ---- epilogue: T_ij = mu_i * U_ij * nu_j ----
    float mu_i[4];
    #pragma unroll
    for (int rr = 0; rr < 4; ++rr)
        mu_i[rr] = mu_s[row0 + rr];          // broadcast read

    float* ob = out + (size_t)b * N_ * N_ + (size_t)row0 * N_ + l;
    #pragma unroll
    for (int q = 0; q < 16; ++q) {
        float nuv = __hip_atomic_load(&nug[b * N_ + l + 64 * q],
                                      __ATOMIC_RELAXED, __HIP_MEMORY_SCOPE_AGENT);
        #pragma unroll
        for (int rr = 0; rr < 4; ++rr)
            ob[(size_t)rr * N_ + 64 * q] = mu_i[rr] * u[rr][q] * nuv;
    }
}

extern "C" void kernel_launch(void* const* d_in, const int* in_sizes, int n_in,
                              void* d_out, int out_size, void* d_ws, size_t ws_size,
                              hipStream_t stream) {
    const float* C = (const float*)d_in[2];     // (B, N, N); x,y unused
    float* out = (float*)d_out;

    unsigned char* ws = (unsigned char*)d_ws;
    unsigned int* cnt = (unsigned int*)ws;
    float* gpart = (float*)(ws + GPART_OFF);
    float* nug   = (float*)(ws + NUG_OFF);

    hipMemsetAsync(cnt, 0, CNT_BYTES, stream);  // barrier counters start at 0
    hipLaunchKernelGGL(sinkhorn_kernel, dim3(256), dim3(1024), 0, stream,
                       C, out, gpart, nug, cnt);
}

// Round 5
// 426.847 us; speedup vs baseline: 6.1458x; 1.2016x over previous
//
#include <hip/hip_runtime.h>
#include <math.h>

#define B_    16
#define N_    1024
#define G_    16      // blocks per batch
#define ITERS 100

// ws layout: [cnt: B_*ITERS u32, pad to 8192][mu_den: 4*B_*N_ f32][nug: B_*N_ f32]
#define MUDEN_OFF   8192
#define MUDEN_BYTES (4 * B_ * N_ * 4)
#define NUG_OFF     (MUDEN_OFF + MUDEN_BYTES)
#define ZERO_BYTES  NUG_OFF     // cnt + all 4 mu_den buffers start at 0

__device__ __forceinline__ float fast_div(float num, float den) {
    float r = __builtin_amdgcn_rcpf(den);
    r = r * (2.0f - den * r);      // one Newton step -> ~full fp32 accuracy
    return num * r;
}

// R4's fence-free structure (proven: 513us). R5's ONLY change: the inter-block
// exchange reduces AT L2 via f32 atomic-add (1 atomic/thread) instead of
// store-16-partials + gather-16 (which cost 16 L2 loads + 15 adds per thread
// per iter). 4-buffer rotation, self-zeroing two iterations ahead.
// Ordering (all fence-free, validated R4): __syncthreads() drains vmcnt per
// wave before s_barrier, so atomics are at the coherence point before tid 0's
// arrival add; readers load only after the poll observes all 16 arrivals.
__global__ __launch_bounds__(1024, 4)
void sinkhorn_kernel(const float* __restrict__ C, float* __restrict__ out,
                     float* __restrict__ mu_den, float* __restrict__ nug,
                     unsigned int* __restrict__ cnt)
{
    __shared__ float part[16 * 1024];   // 64 KB: per-wave column-partial slabs
    __shared__ float mu_s[N_];          // 4 KB: current mu (no aliasing)

    const int tid = threadIdx.x;
    const int w   = tid >> 6;        // wave 0..15 -> 4-row group
    const int l   = tid & 63;
    // XCD-affinity swizzle: batch b's 16 blocks share bid%8 -> same XCD L2
    const int bid = blockIdx.x;
    const int xx = bid & 7, ss = bid >> 3;
    const int b = xx + ((ss >> 4) << 3);
    const int g = ss & 15;
    const int row0 = 64 * g + 4 * w;
    const float cons = 1.0f / 1024.0f;

    // ---- one-time: U tile = exp(-C/eps) into registers ----
    float u[4][16];
    {
        const float* Cb = C + (size_t)b * N_ * N_ + (size_t)row0 * N_ + l;
        #pragma unroll
        for (int rr = 0; rr < 4; ++rr)
            #pragma unroll
            for (int q = 0; q < 16; ++q)
                u[rr][q] = expf(-20.0f * Cb[(size_t)rr * N_ + 64 * q]);
    }

    mu_s[tid] = cons;
    __syncthreads();

    for (int it = 0; it < ITERS; ++it) {
        // ---- Phase A: s_i = sum_j U_ij * mu_j (conflict-free LDS reads) ----
        float a0 = 0.f, a1 = 0.f, a2 = 0.f, a3 = 0.f;
        #pragma unroll
        for (int q = 0; q < 16; ++q) {
            float m = mu_s[l + 64 * q];
            a0 += u[0][q] * m;
            a1 += u[1][q] * m;
            a2 += u[2][q] * m;
            a3 += u[3][q] * m;
        }
        #pragma unroll
        for (int off = 1; off < 64; off <<= 1) {
            a0 += __shfl_xor(a0, off, 64);
            a1 += __shfl_xor(a1, off, 64);
            a2 += __shfl_xor(a2, off, 64);
            a3 += __shfl_xor(a3, off, 64);
        }
        float nu0 = fast_div(cons, a0);
        float nu1 = fast_div(cons, a1);
        float nu2 = fast_div(cons, a2);
        float nu3 = fast_div(cons, a3);

        if (it == ITERS - 1 && l < 4) {   // publish final nu chunk (coherent)
            float nv = (l == 0) ? nu0 : (l == 1) ? nu1 : (l == 2) ? nu2 : nu3;
            __hip_atomic_store(&nug[b * N_ + row0 + l], nv,
                               __ATOMIC_RELAXED, __HIP_MEMORY_SCOPE_AGENT);
        }

        // ---- Phase B: per-wave column partials -> LDS slab (conflict-free) ----
        // (no sync needed before this: part[] and mu_s[] are separate arrays,
        //  and iter it's colsum reads finished before S2 of iter it-1 < here)
        #pragma unroll
        for (int q = 0; q < 16; ++q) {
            float p = u[0][q]*nu0 + u[1][q]*nu1 + u[2][q]*nu2 + u[3][q]*nu3;
            part[w * 1024 + l + 64 * q] = p;
        }
        __syncthreads();   // S1: slabs complete

        // column sums across 16 slabs; reduce at L2 with one f32 atomic/thread
        const int buf = it & 3;
        {
            float ssum = 0.f;
            #pragma unroll
            for (int w2 = 0; w2 < 16; ++w2)
                ssum += part[w2 * 1024 + tid];      // conflict-free
            unsafeAtomicAdd(&mu_den[((size_t)buf * B_ + b) * N_ + tid], ssum);
        }

        // ---- fence-free device barrier among the 16 blocks of batch b ----
        __syncthreads();   // S2: each wave's vmcnt(0) -> adds at coherence pt
        if (tid == 0) {
            unsigned int* c = &cnt[b * ITERS + it];
            __hip_atomic_fetch_add(c, 1u, __ATOMIC_RELAXED, __HIP_MEMORY_SCOPE_AGENT);
            while (__hip_atomic_load(c, __ATOMIC_RELAXED, __HIP_MEMORY_SCOPE_AGENT) < G_)
                __builtin_amdgcn_s_sleep(1);
        }
        __syncthreads();   // S3

        // ---- single readback -> new mu; zero the buffer for iter it+2 ----
        {
            float den = __hip_atomic_load(&mu_den[((size_t)buf * B_ + b) * N_ + tid],
                                          __ATOMIC_RELAXED, __HIP_MEMORY_SCOPE_AGENT);
            mu_s[tid] = fast_div(cons, den);
        }
        if (tid < 64)   // my block's 1/16 share of the buffer reused at it+2
            __hip_atomic_store(&mu_den[((size_t)((it + 2) & 3) * B_ + b) * N_ + 64 * g + tid],
                               0.0f, __ATOMIC_RELAXED, __HIP_MEMORY_SCOPE_AGENT);
        __syncthreads();   // S4: mu_s ready for next phase A
    }

    // ---- epilogue: T_ij = mu_i * U_ij * nu_j ----
    float mu_i[4];
    #pragma unroll
    for (int rr = 0; rr < 4; ++rr)
        mu_i[rr] = mu_s[row0 + rr];          // broadcast read

    float* ob = out + (size_t)b * N_ * N_ + (size_t)row0 * N_ + l;
    #pragma unroll
    for (int q = 0; q < 16; ++q) {
        float nuv = __hip_atomic_load(&nug[b * N_ + l + 64 * q],
                                      __ATOMIC_RELAXED, __HIP_MEMORY_SCOPE_AGENT);
        #pragma unroll
        for (int rr = 0; rr < 4; ++rr)
            ob[(size_t)rr * N_ + 64 * q] = mu_i[rr] * u[rr][q] * nuv;
    }
}

extern "C" void kernel_launch(void* const* d_in, const int* in_sizes, int n_in,
                              void* d_out, int out_size, void* d_ws, size_t ws_size,
                              hipStream_t stream) {
    const float* C = (const float*)d_in[2];     // (B, N, N); x,y unused
    float* out = (float*)d_out;

    unsigned char* ws = (unsigned char*)d_ws;
    unsigned int* cnt = (unsigned int*)ws;
    float* mu_den = (float*)(ws + MUDEN_OFF);
    float* nug    = (float*)(ws + NUG_OFF);

    // cnt + mu_den buffers must start at zero (buffers 2,3 are re-zeroed
    // in-kernel during iters 0,1 as part of the rotation anyway)
    hipMemsetAsync(ws, 0, ZERO_BYTES, stream);
    hipLaunchKernelGGL(sinkhorn_kernel, dim3(256), dim3(1024), 0, stream,
                       C, out, mu_den, nug, cnt);
}